// Round 11
// baseline (260.250 us; speedup 1.0000x reference)
//
#include <hip/hip_runtime.h>
#include <hip/hip_bf16.h>

typedef __attribute__((ext_vector_type(8))) short bf16x8;
typedef __attribute__((ext_vector_type(4))) float f32x4;
typedef __attribute__((ext_vector_type(16))) float f32x16;
typedef __attribute__((ext_vector_type(4))) int i32x4;

#define LOG2E 1.4426950408889634f

__device__ __forceinline__ short f2bf(float f){
  unsigned u = __float_as_uint(f);
  u += 0x7fffu + ((u >> 16) & 1u);
  return (short)(u >> 16);
}
__device__ __forceinline__ unsigned cvtpk(float lo, float hi){
  unsigned r;
  asm("v_cvt_pk_bf16_f32 %0, %1, %2" : "=v"(r) : "v"(lo), "v"(hi));
  return r;
}
__device__ __forceinline__ void plswap(unsigned &a, unsigned &b){
  asm("v_permlane32_swap_b32 %0, %1" : "+v"(a), "+v"(b));
}
__device__ __forceinline__ void gl_lds16(const short* g, short* l){
  __builtin_amdgcn_global_load_lds((const __attribute__((address_space(1))) void*)g,
                                   (__attribute__((address_space(3))) void*)l, 16, 0, 0);
}

// ---------------- fused prep: xconv3 (bid<4096) + W_QKV transpose + W_O transpose ----------------
__global__ __launch_bounds__(256) void prep_all(const float* __restrict__ xq,
                                                const float* __restrict__ xk,
                                                const float* __restrict__ xv,
                                                short* __restrict__ oq,
                                                short* __restrict__ ok,
                                                short* __restrict__ ov,
                                                const float* __restrict__ Wq,
                                                const float* __restrict__ Wk,
                                                const float* __restrict__ Wv,
                                                short* __restrict__ WqT,
                                                short* __restrict__ WkT,
                                                short* __restrict__ WvT,
                                                const float* __restrict__ Wo,
                                                short* __restrict__ WoT){
  __shared__ short t[64][72];
  int bid = blockIdx.x;
  int tid = threadIdx.x;
  if (bid < 4096){
    int idx = (bid * 256 + tid) * 8;
    #pragma unroll
    for (int a = 0; a < 3; ++a){
      const float* x = a == 0 ? xq : (a == 1 ? xk : xv);
      short* o = a == 0 ? oq : (a == 1 ? ok : ov);
      float4 v0 = *(const float4*)&x[idx];
      float4 v1 = *(const float4*)&x[idx + 4];
      bf16x8 tt;
      tt[0]=f2bf(v0.x); tt[1]=f2bf(v0.y); tt[2]=f2bf(v0.z); tt[3]=f2bf(v0.w);
      tt[4]=f2bf(v1.x); tt[5]=f2bf(v1.y); tt[6]=f2bf(v1.z); tt[7]=f2bf(v1.w);
      *(bf16x8*)&o[idx] = tt;
    }
  } else if (bid < 4352){
    int b2 = bid - 4096;
    int h = b2 >> 4, et = b2 & 15;
    int er = tid >> 2, qc = (tid & 3) * 16;
    #pragma unroll
    for (int a = 0; a < 3; ++a){
      const float* W = a == 0 ? Wq : (a == 1 ? Wk : Wv);
      short* Wt = a == 0 ? WqT : (a == 1 ? WkT : WvT);
      if (a) __syncthreads();
      const float* src = W + h * 65536 + (et * 64 + er) * 64 + qc;
      #pragma unroll
      for (int v = 0; v < 4; ++v){
        float4 f = *(const float4*)(src + v * 4);
        t[qc + v * 4 + 0][er] = f2bf(f.x);
        t[qc + v * 4 + 1][er] = f2bf(f.y);
        t[qc + v * 4 + 2][er] = f2bf(f.z);
        t[qc + v * 4 + 3][er] = f2bf(f.w);
      }
      __syncthreads();
      bf16x8 o0 = *(const bf16x8*)&t[er][qc];
      bf16x8 o1 = *(const bf16x8*)&t[er][qc + 8];
      size_t dst = (size_t)(h * 64 + er) * 1024 + et * 64 + qc;
      *(bf16x8*)&Wt[dst] = o0;
      *(bf16x8*)&Wt[dst + 8] = o1;
    }
  } else {
    int b2 = bid - 4352;
    int bi = b2 >> 4, bj = b2 & 15;
    int r = tid >> 2, qc = (tid & 3) * 16;
    const float* src = Wo + (size_t)(bi * 64 + r) * 1024 + bj * 64 + qc;
    #pragma unroll
    for (int v = 0; v < 4; ++v){
      float4 f = *(const float4*)(src + v * 4);
      t[qc + v * 4 + 0][r] = f2bf(f.x);
      t[qc + v * 4 + 1][r] = f2bf(f.y);
      t[qc + v * 4 + 2][r] = f2bf(f.z);
      t[qc + v * 4 + 3][r] = f2bf(f.w);
    }
    __syncthreads();
    bf16x8 o0 = *(const bf16x8*)&t[r][qc];
    bf16x8 o1 = *(const bf16x8*)&t[r][qc + 8];
    size_t dst = (size_t)(bj * 64 + r) * 1024 + bi * 64 + qc;
    *(bf16x8*)&WoT[dst] = o0;
    *(bf16x8*)&WoT[dst + 8] = o1;
  }
}

// ---------------- fused QKV projection GEMM (blockIdx.z selects stream) ----------------
__global__ __launch_bounds__(256) void proj3(const short* __restrict__ Xq,
                                             const short* __restrict__ Xk,
                                             const short* __restrict__ Xv,
                                             const short* __restrict__ WqT,
                                             const short* __restrict__ WkT,
                                             const short* __restrict__ WvT,
                                             const float* __restrict__ bq,
                                             const float* __restrict__ bk,
                                             const float* __restrict__ bv,
                                             short* __restrict__ Oq,
                                             short* __restrict__ Ok,
                                             short* __restrict__ Ov){
  __shared__ short Al[128][64];
  __shared__ short Bl[128][64];
  int z = blockIdx.z;
  const short* A    = z == 0 ? Xq : (z == 1 ? Xk : Xv);
  const short* Wt   = z == 0 ? WqT : (z == 1 ? WkT : WvT);
  const float* bias = z == 0 ? bq : (z == 1 ? bk : bv);
  short* Out        = z == 0 ? Oq : (z == 1 ? Ok : Ov);
  float scale = z == 0 ? (LOG2E * 0.125f) : 1.0f;

  int tid = threadIdx.x;
  int bm0 = blockIdx.x * 128, bn0 = blockIdx.y * 128;
  int w = tid >> 6, lane = tid & 63;
  int wm = w >> 1, wn = w & 1;
  int r16 = lane & 15, kblk = lane >> 4;
  int srow = tid >> 3, schunk = tid & 7;

  f32x4 acc[4][4] = {};
  for (int kt = 0; kt < 16; ++kt){
    int k0 = kt * 64;
    __syncthreads();
    #pragma unroll
    for (int p = 0; p < 4; ++p){
      int row = p * 32 + srow;
      int sc = (schunk ^ (row & 7)) * 8;
      gl_lds16(A  + (size_t)(bm0 + row) * 1024 + k0 + sc, &Al[p * 32 + w * 8][0]);
      gl_lds16(Wt + (size_t)(bn0 + row) * 1024 + k0 + sc, &Bl[p * 32 + w * 8][0]);
    }
    __syncthreads();
    bf16x8 af[2][4], bfr[2][4];
    #pragma unroll
    for (int half = 0; half < 2; ++half){
      #pragma unroll
      for (int m = 0; m < 4; ++m){
        int r = wm * 64 + m * 16 + r16;
        af[half][m] = *(bf16x8*)&Al[r][(((half << 2) | kblk) ^ (r & 7)) * 8];
      }
      #pragma unroll
      for (int n = 0; n < 4; ++n){
        int r = wn * 64 + n * 16 + r16;
        bfr[half][n] = *(bf16x8*)&Bl[r][(((half << 2) | kblk) ^ (r & 7)) * 8];
      }
    }
    #pragma unroll
    for (int half = 0; half < 2; ++half)
      #pragma unroll
      for (int m = 0; m < 4; ++m)
        #pragma unroll
        for (int n = 0; n < 4; ++n)
          acc[m][n] = __builtin_amdgcn_mfma_f32_16x16x32_bf16(af[half][m], bfr[half][n], acc[m][n], 0, 0, 0);
  }
  if (z != 2){
    #pragma unroll
    for (int m = 0; m < 4; ++m){
      int grow0 = bm0 + wm * 64 + m * 16 + kblk * 4;
      #pragma unroll
      for (int n = 0; n < 4; ++n){
        int gcol = bn0 + wn * 64 + n * 16 + r16;
        float bv_ = bias[gcol];
        int h = gcol >> 6, d = gcol & 63;
        #pragma unroll
        for (int i = 0; i < 4; ++i){
          int grow = grow0 + i;
          int b = grow >> 11, s = grow & 2047;
          Out[(size_t)((b * 16 + h) * 2048 + s) * 64 + d] = f2bf((acc[m][n][i] + bv_) * scale);
        }
      }
    }
  } else {
    #pragma unroll
    for (int m = 0; m < 4; ++m){
      int grow0 = bm0 + wm * 64 + m * 16 + kblk * 4;
      int b = grow0 >> 11, s = grow0 & 2047;
      #pragma unroll
      for (int n = 0; n < 4; ++n){
        int gcol = bn0 + wn * 64 + n * 16 + r16;
        float bv_ = bias[gcol];
        int h = gcol >> 6, d = gcol & 63;
        short4 o = make_short4(f2bf(acc[m][n][0] + bv_),
                               f2bf(acc[m][n][1] + bv_),
                               f2bf(acc[m][n][2] + bv_),
                               f2bf(acc[m][n][3] + bv_));
        *(short4*)&Out[(size_t)((b * 16 + h) * 64 + d) * 2048 + s] = o;
      }
    }
  }
}

// ---------------- output projection GEMM ----------------
__global__ __launch_bounds__(256) void out_gemm(const short* __restrict__ A,
                                                const short* __restrict__ Wt,
                                                const float* __restrict__ bias,
                                                float* __restrict__ Out){
  __shared__ short Al[128][64];
  __shared__ short Bl[128][64];
  int tid = threadIdx.x;
  int bm0 = blockIdx.x * 128, bn0 = blockIdx.y * 128;
  int w = tid >> 6, lane = tid & 63;
  int wm = w >> 1, wn = w & 1;
  int r16 = lane & 15, kblk = lane >> 4;
  int srow = tid >> 3, schunk = tid & 7;
  f32x4 acc[4][4] = {};
  for (int kt = 0; kt < 16; ++kt){
    int k0 = kt * 64;
    __syncthreads();
    #pragma unroll
    for (int p = 0; p < 4; ++p){
      int row = p * 32 + srow;
      int sc = (schunk ^ (row & 7)) * 8;
      gl_lds16(A  + (size_t)(bm0 + row) * 1024 + k0 + sc, &Al[p * 32 + w * 8][0]);
      gl_lds16(Wt + (size_t)(bn0 + row) * 1024 + k0 + sc, &Bl[p * 32 + w * 8][0]);
    }
    __syncthreads();
    bf16x8 af[2][4], bfr[2][4];
    #pragma unroll
    for (int half = 0; half < 2; ++half){
      #pragma unroll
      for (int m = 0; m < 4; ++m){
        int r = wm * 64 + m * 16 + r16;
        af[half][m] = *(bf16x8*)&Al[r][(((half << 2) | kblk) ^ (r & 7)) * 8];
      }
      #pragma unroll
      for (int n = 0; n < 4; ++n){
        int r = wn * 64 + n * 16 + r16;
        bfr[half][n] = *(bf16x8*)&Bl[r][(((half << 2) | kblk) ^ (r & 7)) * 8];
      }
    }
    #pragma unroll
    for (int half = 0; half < 2; ++half)
      #pragma unroll
      for (int m = 0; m < 4; ++m)
        #pragma unroll
        for (int n = 0; n < 4; ++n)
          acc[m][n] = __builtin_amdgcn_mfma_f32_16x16x32_bf16(af[half][m], bfr[half][n], acc[m][n], 0, 0, 0);
  }
  #pragma unroll
  for (int m = 0; m < 4; ++m){
    int grow0 = bm0 + wm * 64 + m * 16 + kblk * 4;
    #pragma unroll
    for (int n = 0; n < 4; ++n){
      int gcol = bn0 + wn * 64 + n * 16 + r16;
      float bv = bias[gcol];
      #pragma unroll
      for (int i = 0; i < 4; ++i)
        Out[(size_t)(grow0 + i) * 1024 + gcol] = acc[m][n][i] + bv;
    }
  }
}

// ---------------- flash attention (hybrid: K via LDS dbuf, V direct-to-reg w/ QK window) ----------------
__device__ __forceinline__ f32x16 mfma32(bf16x8 a, bf16x8 b, f32x16 c){
  return __builtin_amdgcn_mfma_f32_32x32x16_bf16(a, b, c, 0, 0, 0);
}

__device__ __forceinline__ void sm_pack(f32x16& s0, f32x16& s1, float& lrow, bf16x8* pb){
  #pragma unroll
  for (int r = 0; r < 16; ++r) s0[r] = __builtin_amdgcn_exp2f(s0[r]);
  #pragma unroll
  for (int r = 0; r < 16; ++r) s1[r] = __builtin_amdgcn_exp2f(s1[r]);
  float u8_[8];
  #pragma unroll
  for (int r = 0; r < 8; ++r)
    u8_[r] = (s0[r] + s0[r + 8]) + (s1[r] + s1[r + 8]);
  float rs = ((u8_[0] + u8_[1]) + (u8_[2] + u8_[3])) + ((u8_[4] + u8_[5]) + (u8_[6] + u8_[7]));
  lrow += rs;                       // per-lane partial; cross-half shfl deferred to epilogue
  #pragma unroll
  for (int cc = 0; cc < 2; ++cc){
    int b0 = cc * 8;
    unsigned u0 = cvtpk(s0[b0 + 0], s0[b0 + 1]);
    unsigned u1 = cvtpk(s0[b0 + 2], s0[b0 + 3]);
    unsigned w0 = cvtpk(s0[b0 + 4], s0[b0 + 5]);
    unsigned w1 = cvtpk(s0[b0 + 6], s0[b0 + 7]);
    plswap(u0, w0); plswap(u1, w1);
    i32x4 pk0; pk0[0] = (int)u0; pk0[1] = (int)u1; pk0[2] = (int)w0; pk0[3] = (int)w1;
    pb[cc] = __builtin_bit_cast(bf16x8, pk0);
    unsigned y0 = cvtpk(s1[b0 + 0], s1[b0 + 1]);
    unsigned y1 = cvtpk(s1[b0 + 2], s1[b0 + 3]);
    unsigned z0 = cvtpk(s1[b0 + 4], s1[b0 + 5]);
    unsigned z1 = cvtpk(s1[b0 + 6], s1[b0 + 7]);
    plswap(y0, z0); plswap(y1, z1);
    i32x4 pk1; pk1[0] = (int)y0; pk1[1] = (int)y1; pk1[2] = (int)z0; pk1[3] = (int)z1;
    pb[2 + cc] = __builtin_bit_cast(bf16x8, pk1);
  }
}

// body: issue V direct loads (consumed at PV, window = QK+softmax) -> stage K t+1 ->
//       QK from Kl[CUR] -> softmax/pack -> PV(vf) -> barrier
#define ATT_BODY(T, CUR, NXT)                                                          \
  {                                                                                    \
    const short* vt0 = V0 + (T) * 64;                                                  \
    const short* vt1 = V1 + (T) * 64;                                                  \
    bf16x8 vfa[4], vfb[4];                                                             \
    _Pragma("unroll")                                                                  \
    for (int c = 0; c < 4; ++c){                                                       \
      vfa[c] = *(const bf16x8*)(vt0 + c * 16);                                         \
      vfb[c] = *(const bf16x8*)(vt1 + c * 16);                                         \
    }                                                                                  \
    if ((T) + 1 < 32){                                                                 \
      _Pragma("unroll")                                                                \
      for (int p = 0; p < 2; ++p){                                                     \
        int row = p * 32 + srow;                                                       \
        gl_lds16(Kp + (size_t)(((T) + 1) * 64 + row) * 64 + sx, &Kl[NXT][p * 32 + w * 8][0]); \
      }                                                                                \
    }                                                                                  \
    f32x16 sA0 = {}, sA1 = {}, sB0 = {}, sB1 = {};                                     \
    _Pragma("unroll")                                                                  \
    for (int c = 0; c < 4; ++c){                                                       \
      bf16x8 kf0 = *(const bf16x8*)&Kl[CUR][l31][rchunk[c]];                           \
      bf16x8 kf1 = *(const bf16x8*)&Kl[CUR][32 + l31][rchunk[c]];                      \
      sA0 = mfma32(kf0, qfA[c], sA0);                                                  \
      sA1 = mfma32(kf1, qfA[c], sA1);                                                  \
      sB0 = mfma32(kf0, qfB[c], sB0);                                                  \
      sB1 = mfma32(kf1, qfB[c], sB1);                                                  \
    }                                                                                  \
    bf16x8 pbA[4], pbB[4];                                                             \
    sm_pack(sA0, sA1, lrowA, pbA);                                                     \
    sm_pack(sB0, sB1, lrowB, pbB);                                                     \
    _Pragma("unroll")                                                                  \
    for (int c = 0; c < 4; ++c){                                                       \
      accA0 = mfma32(vfa[c], pbA[c], accA0);                                           \
      accA1 = mfma32(vfb[c], pbA[c], accA1);                                           \
      accB0 = mfma32(vfa[c], pbB[c], accB0);                                           \
      accB1 = mfma32(vfb[c], pbB[c], accB1);                                           \
    }                                                                                  \
    __syncthreads();                                                                   \
  }

__global__ __launch_bounds__(256, 2) void attn(const short* __restrict__ Qb,
                                               const short* __restrict__ Kb,
                                               const short* __restrict__ Vtb,
                                               short* __restrict__ OVb){
  __shared__ short Kl[2][64][64];
  int tid = threadIdx.x;
  int w = tid >> 6, lane = tid & 63;
  int l31 = lane & 31, hi = lane >> 5;
  int bh = blockIdx.x & 63, qb = blockIdx.x >> 6;   // qb 0..7
  const short* Qp = Qb + ((size_t)bh * 2048 + qb * 256 + w * 64) * 64;
  const short* Kp = Kb + (size_t)bh * 2048 * 64;
  // V^T direct per-lane bases (round-10-validated addresses)
  const short* V0 = Vtb + (size_t)bh * 64 * 2048 + (size_t)l31 * 2048 + hi * 8;
  const short* V1 = V0 + (size_t)32 * 2048;
  int srow = tid >> 3, schunk = tid & 7;
  int sx = (schunk ^ (srow & 7)) * 8;

  int rchunk[4];
  #pragma unroll
  for (int c = 0; c < 4; ++c) rchunk[c] = (((c << 1) | hi) ^ (l31 & 7)) * 8;

  // prefetch K tile 0 into buf 0
  #pragma unroll
  for (int p = 0; p < 2; ++p){
    int row = p * 32 + srow;
    gl_lds16(Kp + (size_t)row * 64 + sx, &Kl[0][p * 32 + w * 8][0]);
  }

  bf16x8 qfA[4], qfB[4];
  #pragma unroll
  for (int c = 0; c < 4; ++c){
    qfA[c] = *(const bf16x8*)&Qp[l31 * 64 + c * 16 + hi * 8];
    qfB[c] = *(const bf16x8*)&Qp[(32 + l31) * 64 + c * 16 + hi * 8];
  }

  f32x16 accA0 = {}, accA1 = {}, accB0 = {}, accB1 = {};
  float lrowA = 0.f, lrowB = 0.f;
  __syncthreads();

  for (int t = 0; t < 32; t += 2){
    ATT_BODY(t, 0, 1)
    ATT_BODY(t + 1, 1, 0)
  }

  lrowA += __shfl_xor(lrowA, 32);
  lrowB += __shfl_xor(lrowB, 32);

  int b = bh >> 4, h = bh & 15;
  int q0 = qb * 256 + w * 64 + l31;
  float invA = 1.0f / lrowA;
  float invB = 1.0f / lrowB;
  size_t baseA = ((size_t)(b * 2048 + q0)) * 1024 + h * 64;
  size_t baseB = baseA + (size_t)32 * 1024;
  #pragma unroll
  for (int rg = 0; rg < 4; ++rg){
    short4 a0 = make_short4(f2bf(accA0[rg * 4 + 0] * invA), f2bf(accA0[rg * 4 + 1] * invA),
                            f2bf(accA0[rg * 4 + 2] * invA), f2bf(accA0[rg * 4 + 3] * invA));
    *(short4*)&OVb[baseA + rg * 8 + hi * 4] = a0;
    short4 a1 = make_short4(f2bf(accA1[rg * 4 + 0] * invA), f2bf(accA1[rg * 4 + 1] * invA),
                            f2bf(accA1[rg * 4 + 2] * invA), f2bf(accA1[rg * 4 + 3] * invA));
    *(short4*)&OVb[baseA + 32 + rg * 8 + hi * 4] = a1;
    short4 b0 = make_short4(f2bf(accB0[rg * 4 + 0] * invB), f2bf(accB0[rg * 4 + 1] * invB),
                            f2bf(accB0[rg * 4 + 2] * invB), f2bf(accB0[rg * 4 + 3] * invB));
    *(short4*)&OVb[baseB + rg * 8 + hi * 4] = b0;
    short4 b1 = make_short4(f2bf(accB1[rg * 4 + 0] * invB), f2bf(accB1[rg * 4 + 1] * invB),
                            f2bf(accB1[rg * 4 + 2] * invB), f2bf(accB1[rg * 4 + 3] * invB));
    *(short4*)&OVb[baseB + 32 + rg * 8 + hi * 4] = b1;
  }
}

extern "C" void kernel_launch(void* const* d_in, const int* in_sizes, int n_in,
                              void* d_out, int out_size, void* d_ws, size_t ws_size,
                              hipStream_t stream) {
  const float* query = (const float*)d_in[0];
  const float* key_  = (const float*)d_in[1];
  const float* value = (const float*)d_in[2];
  const float* W_Q = (const float*)d_in[3];
  const float* W_K = (const float*)d_in[4];
  const float* W_V = (const float*)d_in[5];
  const float* W_O = (const float*)d_in[6];
  const float* b_Q = (const float*)d_in[7];
  const float* b_K = (const float*)d_in[8];
  const float* b_V = (const float*)d_in[9];
  const float* b_O = (const float*)d_in[10];

  char* ws = (char*)d_ws;
  const size_t MB2 = 2097152, MB16 = 16777216;
  short* WqT = (short*)(ws + 0);
  short* WkT = (short*)(ws + MB2);
  short* WvT = (short*)(ws + 2 * MB2);
  short* WoT = (short*)(ws + 3 * MB2);
  short* Xq = (short*)(ws + 4 * MB2);
  short* Xk = (short*)(ws + 4 * MB2 + MB16);
  short* Xv = (short*)(ws + 4 * MB2 + 2 * MB16);
  bool big = ws_size >= (size_t)(4 * MB2 + 6 * MB16);
  short* Qb  = (short*)(ws + 4 * MB2 + 3 * MB16);
  short* Kb  = big ? (short*)(ws + 4 * MB2 + 4 * MB16) : Xq;
  short* Vtb = big ? (short*)(ws + 4 * MB2 + 5 * MB16) : Xk;
  short* OVb = Xv;   // attn output overwrites Xv (dead by then)

  prep_all<<<4608, 256, 0, stream>>>(query, key_, value, Xq, Xk, Xv,
                                     W_Q, W_K, W_V, WqT, WkT, WvT, W_O, WoT);

  if (big){
    proj3<<<dim3(64, 8, 3), 256, 0, stream>>>(Xq, Xk, Xv, WqT, WkT, WvT,
                                              b_Q, b_K, b_V, Qb, Kb, Vtb);
  } else {
    proj3<<<dim3(64, 8, 1), 256, 0, stream>>>(Xq, Xk, Xv, WqT, WkT, WvT, b_Q, b_K, b_V, Qb, Kb, Vtb);
    proj3<<<dim3(64, 8, 1), 256, 0, stream>>>(Xk, Xk, Xv, WkT, WkT, WvT, b_K, b_K, b_V, Kb, Kb, Vtb);
    proj3<<<dim3(64, 8, 1), 256, 0, stream>>>(Xv, Xk, Xv, WvT, WkT, WvT, b_V, b_K, b_V, Vtb, Kb, Vtb);
  }

  attn<<<512, 256, 0, stream>>>(Qb, Kb, Vtb, OVb);

  out_gemm<<<dim3(64, 8), 256, 0, stream>>>(OVb, WoT, b_O, (float*)d_out);
}

// Round 12
// 193.716 us; speedup vs baseline: 1.3435x; 1.3435x over previous
//
#include <hip/hip_runtime.h>
#include <hip/hip_bf16.h>

typedef __attribute__((ext_vector_type(8))) short bf16x8;
typedef __attribute__((ext_vector_type(4))) float f32x4;
typedef __attribute__((ext_vector_type(16))) float f32x16;
typedef __attribute__((ext_vector_type(4))) int i32x4;

#define LOG2E 1.4426950408889634f

__device__ __forceinline__ short f2bf(float f){
  unsigned u = __float_as_uint(f);
  u += 0x7fffu + ((u >> 16) & 1u);
  return (short)(u >> 16);
}
__device__ __forceinline__ unsigned cvtpk(float lo, float hi){
  unsigned r;
  asm("v_cvt_pk_bf16_f32 %0, %1, %2" : "=v"(r) : "v"(lo), "v"(hi));
  return r;
}
__device__ __forceinline__ void plswap(unsigned &a, unsigned &b){
  asm("v_permlane32_swap_b32 %0, %1" : "+v"(a), "+v"(b));
}
__device__ __forceinline__ void gl_lds16(const short* g, short* l){
  __builtin_amdgcn_global_load_lds((const __attribute__((address_space(1))) void*)g,
                                   (__attribute__((address_space(3))) void*)l, 16, 0, 0);
}

// ---------------- fused prep: xconv3 (bid<4096) + W_QKV transpose + W_O transpose ----------------
__global__ __launch_bounds__(256) void prep_all(const float* __restrict__ xq,
                                                const float* __restrict__ xk,
                                                const float* __restrict__ xv,
                                                short* __restrict__ oq,
                                                short* __restrict__ ok,
                                                short* __restrict__ ov,
                                                const float* __restrict__ Wq,
                                                const float* __restrict__ Wk,
                                                const float* __restrict__ Wv,
                                                short* __restrict__ WqT,
                                                short* __restrict__ WkT,
                                                short* __restrict__ WvT,
                                                const float* __restrict__ Wo,
                                                short* __restrict__ WoT){
  __shared__ short t[64][72];
  int bid = blockIdx.x;
  int tid = threadIdx.x;
  if (bid < 4096){
    int idx = (bid * 256 + tid) * 8;
    #pragma unroll
    for (int a = 0; a < 3; ++a){
      const float* x = a == 0 ? xq : (a == 1 ? xk : xv);
      short* o = a == 0 ? oq : (a == 1 ? ok : ov);
      float4 v0 = *(const float4*)&x[idx];
      float4 v1 = *(const float4*)&x[idx + 4];
      bf16x8 tt;
      tt[0]=f2bf(v0.x); tt[1]=f2bf(v0.y); tt[2]=f2bf(v0.z); tt[3]=f2bf(v0.w);
      tt[4]=f2bf(v1.x); tt[5]=f2bf(v1.y); tt[6]=f2bf(v1.z); tt[7]=f2bf(v1.w);
      *(bf16x8*)&o[idx] = tt;
    }
  } else if (bid < 4352){
    int b2 = bid - 4096;
    int h = b2 >> 4, et = b2 & 15;
    int er = tid >> 2, qc = (tid & 3) * 16;
    #pragma unroll
    for (int a = 0; a < 3; ++a){
      const float* W = a == 0 ? Wq : (a == 1 ? Wk : Wv);
      short* Wt = a == 0 ? WqT : (a == 1 ? WkT : WvT);
      if (a) __syncthreads();
      const float* src = W + h * 65536 + (et * 64 + er) * 64 + qc;
      #pragma unroll
      for (int v = 0; v < 4; ++v){
        float4 f = *(const float4*)(src + v * 4);
        t[qc + v * 4 + 0][er] = f2bf(f.x);
        t[qc + v * 4 + 1][er] = f2bf(f.y);
        t[qc + v * 4 + 2][er] = f2bf(f.z);
        t[qc + v * 4 + 3][er] = f2bf(f.w);
      }
      __syncthreads();
      bf16x8 o0 = *(const bf16x8*)&t[er][qc];
      bf16x8 o1 = *(const bf16x8*)&t[er][qc + 8];
      size_t dst = (size_t)(h * 64 + er) * 1024 + et * 64 + qc;
      *(bf16x8*)&Wt[dst] = o0;
      *(bf16x8*)&Wt[dst + 8] = o1;
    }
  } else {
    int b2 = bid - 4352;
    int bi = b2 >> 4, bj = b2 & 15;
    int r = tid >> 2, qc = (tid & 3) * 16;
    const float* src = Wo + (size_t)(bi * 64 + r) * 1024 + bj * 64 + qc;
    #pragma unroll
    for (int v = 0; v < 4; ++v){
      float4 f = *(const float4*)(src + v * 4);
      t[qc + v * 4 + 0][r] = f2bf(f.x);
      t[qc + v * 4 + 1][r] = f2bf(f.y);
      t[qc + v * 4 + 2][r] = f2bf(f.z);
      t[qc + v * 4 + 3][r] = f2bf(f.w);
    }
    __syncthreads();
    bf16x8 o0 = *(const bf16x8*)&t[r][qc];
    bf16x8 o1 = *(const bf16x8*)&t[r][qc + 8];
    size_t dst = (size_t)(bj * 64 + r) * 1024 + bi * 64 + qc;
    *(bf16x8*)&WoT[dst] = o0;
    *(bf16x8*)&WoT[dst + 8] = o1;
  }
}

// ---------------- fused QKV projection GEMM (blockIdx.z selects stream) ----------------
__global__ __launch_bounds__(256) void proj3(const short* __restrict__ Xq,
                                             const short* __restrict__ Xk,
                                             const short* __restrict__ Xv,
                                             const short* __restrict__ WqT,
                                             const short* __restrict__ WkT,
                                             const short* __restrict__ WvT,
                                             const float* __restrict__ bq,
                                             const float* __restrict__ bk,
                                             const float* __restrict__ bv,
                                             short* __restrict__ Oq,
                                             short* __restrict__ Ok,
                                             short* __restrict__ Ov){
  __shared__ short Al[128][64];
  __shared__ short Bl[128][64];
  int z = blockIdx.z;
  const short* A    = z == 0 ? Xq : (z == 1 ? Xk : Xv);
  const short* Wt   = z == 0 ? WqT : (z == 1 ? WkT : WvT);
  const float* bias = z == 0 ? bq : (z == 1 ? bk : bv);
  short* Out        = z == 0 ? Oq : (z == 1 ? Ok : Ov);
  float scale = z == 0 ? (LOG2E * 0.125f) : 1.0f;

  int tid = threadIdx.x;
  int bm0 = blockIdx.x * 128, bn0 = blockIdx.y * 128;
  int w = tid >> 6, lane = tid & 63;
  int wm = w >> 1, wn = w & 1;
  int r16 = lane & 15, kblk = lane >> 4;
  int srow = tid >> 3, schunk = tid & 7;

  f32x4 acc[4][4] = {};
  for (int kt = 0; kt < 16; ++kt){
    int k0 = kt * 64;
    __syncthreads();
    #pragma unroll
    for (int p = 0; p < 4; ++p){
      int row = p * 32 + srow;
      int sc = (schunk ^ (row & 7)) * 8;
      gl_lds16(A  + (size_t)(bm0 + row) * 1024 + k0 + sc, &Al[p * 32 + w * 8][0]);
      gl_lds16(Wt + (size_t)(bn0 + row) * 1024 + k0 + sc, &Bl[p * 32 + w * 8][0]);
    }
    __syncthreads();
    bf16x8 af[2][4], bfr[2][4];
    #pragma unroll
    for (int half = 0; half < 2; ++half){
      #pragma unroll
      for (int m = 0; m < 4; ++m){
        int r = wm * 64 + m * 16 + r16;
        af[half][m] = *(bf16x8*)&Al[r][(((half << 2) | kblk) ^ (r & 7)) * 8];
      }
      #pragma unroll
      for (int n = 0; n < 4; ++n){
        int r = wn * 64 + n * 16 + r16;
        bfr[half][n] = *(bf16x8*)&Bl[r][(((half << 2) | kblk) ^ (r & 7)) * 8];
      }
    }
    #pragma unroll
    for (int half = 0; half < 2; ++half)
      #pragma unroll
      for (int m = 0; m < 4; ++m)
        #pragma unroll
        for (int n = 0; n < 4; ++n)
          acc[m][n] = __builtin_amdgcn_mfma_f32_16x16x32_bf16(af[half][m], bfr[half][n], acc[m][n], 0, 0, 0);
  }
  if (z != 2){
    #pragma unroll
    for (int m = 0; m < 4; ++m){
      int grow0 = bm0 + wm * 64 + m * 16 + kblk * 4;
      #pragma unroll
      for (int n = 0; n < 4; ++n){
        int gcol = bn0 + wn * 64 + n * 16 + r16;
        float bv_ = bias[gcol];
        int h = gcol >> 6, d = gcol & 63;
        #pragma unroll
        for (int i = 0; i < 4; ++i){
          int grow = grow0 + i;
          int b = grow >> 11, s = grow & 2047;
          Out[(size_t)((b * 16 + h) * 2048 + s) * 64 + d] = f2bf((acc[m][n][i] + bv_) * scale);
        }
      }
    }
  } else {
    #pragma unroll
    for (int m = 0; m < 4; ++m){
      int grow0 = bm0 + wm * 64 + m * 16 + kblk * 4;
      int b = grow0 >> 11, s = grow0 & 2047;
      #pragma unroll
      for (int n = 0; n < 4; ++n){
        int gcol = bn0 + wn * 64 + n * 16 + r16;
        float bv_ = bias[gcol];
        int h = gcol >> 6, d = gcol & 63;
        short4 o = make_short4(f2bf(acc[m][n][0] + bv_),
                               f2bf(acc[m][n][1] + bv_),
                               f2bf(acc[m][n][2] + bv_),
                               f2bf(acc[m][n][3] + bv_));
        *(short4*)&Out[(size_t)((b * 16 + h) * 64 + d) * 2048 + s] = o;
      }
    }
  }
}

// ---------------- output projection GEMM ----------------
__global__ __launch_bounds__(256) void out_gemm(const short* __restrict__ A,
                                                const short* __restrict__ Wt,
                                                const float* __restrict__ bias,
                                                float* __restrict__ Out){
  __shared__ short Al[128][64];
  __shared__ short Bl[128][64];
  int tid = threadIdx.x;
  int bm0 = blockIdx.x * 128, bn0 = blockIdx.y * 128;
  int w = tid >> 6, lane = tid & 63;
  int wm = w >> 1, wn = w & 1;
  int r16 = lane & 15, kblk = lane >> 4;
  int srow = tid >> 3, schunk = tid & 7;
  f32x4 acc[4][4] = {};
  for (int kt = 0; kt < 16; ++kt){
    int k0 = kt * 64;
    __syncthreads();
    #pragma unroll
    for (int p = 0; p < 4; ++p){
      int row = p * 32 + srow;
      int sc = (schunk ^ (row & 7)) * 8;
      gl_lds16(A  + (size_t)(bm0 + row) * 1024 + k0 + sc, &Al[p * 32 + w * 8][0]);
      gl_lds16(Wt + (size_t)(bn0 + row) * 1024 + k0 + sc, &Bl[p * 32 + w * 8][0]);
    }
    __syncthreads();
    bf16x8 af[2][4], bfr[2][4];
    #pragma unroll
    for (int half = 0; half < 2; ++half){
      #pragma unroll
      for (int m = 0; m < 4; ++m){
        int r = wm * 64 + m * 16 + r16;
        af[half][m] = *(bf16x8*)&Al[r][(((half << 2) | kblk) ^ (r & 7)) * 8];
      }
      #pragma unroll
      for (int n = 0; n < 4; ++n){
        int r = wn * 64 + n * 16 + r16;
        bfr[half][n] = *(bf16x8*)&Bl[r][(((half << 2) | kblk) ^ (r & 7)) * 8];
      }
    }
    #pragma unroll
    for (int half = 0; half < 2; ++half)
      #pragma unroll
      for (int m = 0; m < 4; ++m)
        #pragma unroll
        for (int n = 0; n < 4; ++n)
          acc[m][n] = __builtin_amdgcn_mfma_f32_16x16x32_bf16(af[half][m], bfr[half][n], acc[m][n], 0, 0, 0);
  }
  #pragma unroll
  for (int m = 0; m < 4; ++m){
    int grow0 = bm0 + wm * 64 + m * 16 + kblk * 4;
    #pragma unroll
    for (int n = 0; n < 4; ++n){
      int gcol = bn0 + wn * 64 + n * 16 + r16;
      float bv = bias[gcol];
      #pragma unroll
      for (int i = 0; i < 4; ++i)
        Out[(size_t)(grow0 + i) * 1024 + gcol] = acc[m][n][i] + bv;
    }
  }
}

// ---------------- flash attention (round-9: K+V LDS dbuf, deferred cross-half shfl) ----------------
__device__ __forceinline__ f32x16 mfma32(bf16x8 a, bf16x8 b, f32x16 c){
  return __builtin_amdgcn_mfma_f32_32x32x16_bf16(a, b, c, 0, 0, 0);
}

__device__ __forceinline__ void sm_pack(f32x16& s0, f32x16& s1, float& lrow, bf16x8* pb){
  #pragma unroll
  for (int r = 0; r < 16; ++r) s0[r] = __builtin_amdgcn_exp2f(s0[r]);
  #pragma unroll
  for (int r = 0; r < 16; ++r) s1[r] = __builtin_amdgcn_exp2f(s1[r]);
  float u8_[8];
  #pragma unroll
  for (int r = 0; r < 8; ++r)
    u8_[r] = (s0[r] + s0[r + 8]) + (s1[r] + s1[r + 8]);
  float rs = ((u8_[0] + u8_[1]) + (u8_[2] + u8_[3])) + ((u8_[4] + u8_[5]) + (u8_[6] + u8_[7]));
  lrow += rs;                       // per-lane partial; cross-half shfl deferred to epilogue
  #pragma unroll
  for (int cc = 0; cc < 2; ++cc){
    int b0 = cc * 8;
    unsigned u0 = cvtpk(s0[b0 + 0], s0[b0 + 1]);
    unsigned u1 = cvtpk(s0[b0 + 2], s0[b0 + 3]);
    unsigned w0 = cvtpk(s0[b0 + 4], s0[b0 + 5]);
    unsigned w1 = cvtpk(s0[b0 + 6], s0[b0 + 7]);
    plswap(u0, w0); plswap(u1, w1);
    i32x4 pk0; pk0[0] = (int)u0; pk0[1] = (int)u1; pk0[2] = (int)w0; pk0[3] = (int)w1;
    pb[cc] = __builtin_bit_cast(bf16x8, pk0);
    unsigned y0 = cvtpk(s1[b0 + 0], s1[b0 + 1]);
    unsigned y1 = cvtpk(s1[b0 + 2], s1[b0 + 3]);
    unsigned z0 = cvtpk(s1[b0 + 4], s1[b0 + 5]);
    unsigned z1 = cvtpk(s1[b0 + 6], s1[b0 + 7]);
    plswap(y0, z0); plswap(y1, z1);
    i32x4 pk1; pk1[0] = (int)y0; pk1[1] = (int)y1; pk1[2] = (int)z0; pk1[3] = (int)z1;
    pb[2 + cc] = __builtin_bit_cast(bf16x8, pk1);
  }
}

#define ATT_BODY(T, CUR, NXT)                                                          \
  {                                                                                    \
    if ((T) + 1 < 32){                                                                 \
      _Pragma("unroll")                                                                \
      for (int p = 0; p < 2; ++p){                                                     \
        int row = p * 32 + srow;                                                       \
        gl_lds16(Kp + (size_t)(((T) + 1) * 64 + row) * 64 + sx, &Kl[NXT][p * 32 + w * 8][0]); \
        gl_lds16(Vp + (size_t)row * 2048 + ((T) + 1) * 64 + sx, &Vl[NXT][p * 32 + w * 8][0]); \
      }                                                                                \
    }                                                                                  \
    f32x16 sA0 = {}, sA1 = {}, sB0 = {}, sB1 = {};                                     \
    _Pragma("unroll")                                                                  \
    for (int c = 0; c < 4; ++c){                                                       \
      bf16x8 kf0 = *(const bf16x8*)&Kl[CUR][l31][rchunk[c]];                           \
      bf16x8 kf1 = *(const bf16x8*)&Kl[CUR][32 + l31][rchunk[c]];                      \
      sA0 = mfma32(kf0, qfA[c], sA0);                                                  \
      sA1 = mfma32(kf1, qfA[c], sA1);                                                  \
      sB0 = mfma32(kf0, qfB[c], sB0);                                                  \
      sB1 = mfma32(kf1, qfB[c], sB1);                                                  \
    }                                                                                  \
    bf16x8 pbA[4], pbB[4];                                                             \
    sm_pack(sA0, sA1, lrowA, pbA);                                                     \
    sm_pack(sB0, sB1, lrowB, pbB);                                                     \
    _Pragma("unroll")                                                                  \
    for (int c = 0; c < 4; ++c){                                                       \
      bf16x8 vf0 = *(const bf16x8*)&Vl[CUR][l31][rchunk[c]];                           \
      bf16x8 vf1 = *(const bf16x8*)&Vl[CUR][32 + l31][rchunk[c]];                      \
      accA0 = mfma32(vf0, pbA[c], accA0);                                              \
      accA1 = mfma32(vf1, pbA[c], accA1);                                              \
      accB0 = mfma32(vf0, pbB[c], accB0);                                              \
      accB1 = mfma32(vf1, pbB[c], accB1);                                              \
    }                                                                                  \
    __syncthreads();                                                                   \
  }

__global__ __launch_bounds__(256, 2) void attn(const short* __restrict__ Qb,
                                               const short* __restrict__ Kb,
                                               const short* __restrict__ Vtb,
                                               short* __restrict__ OVb){
  __shared__ short Kl[2][64][64];
  __shared__ short Vl[2][64][64];
  int tid = threadIdx.x;
  int w = tid >> 6, lane = tid & 63;
  int l31 = lane & 31, hi = lane >> 5;
  int bh = blockIdx.x & 63, qb = blockIdx.x >> 6;   // qb 0..7
  const short* Qp = Qb + ((size_t)bh * 2048 + qb * 256 + w * 64) * 64;
  const short* Kp = Kb + (size_t)bh * 2048 * 64;
  const short* Vp = Vtb + (size_t)bh * 64 * 2048;
  int srow = tid >> 3, schunk = tid & 7;
  int sx = (schunk ^ (srow & 7)) * 8;

  int rchunk[4];
  #pragma unroll
  for (int c = 0; c < 4; ++c) rchunk[c] = (((c << 1) | hi) ^ (l31 & 7)) * 8;

  #pragma unroll
  for (int p = 0; p < 2; ++p){
    int row = p * 32 + srow;
    gl_lds16(Kp + (size_t)row * 64 + sx, &Kl[0][p * 32 + w * 8][0]);
    gl_lds16(Vp + (size_t)row * 2048 + sx, &Vl[0][p * 32 + w * 8][0]);
  }

  bf16x8 qfA[4], qfB[4];
  #pragma unroll
  for (int c = 0; c < 4; ++c){
    qfA[c] = *(const bf16x8*)&Qp[l31 * 64 + c * 16 + hi * 8];
    qfB[c] = *(const bf16x8*)&Qp[(32 + l31) * 64 + c * 16 + hi * 8];
  }

  f32x16 accA0 = {}, accA1 = {}, accB0 = {}, accB1 = {};
  float lrowA = 0.f, lrowB = 0.f;
  __syncthreads();

  for (int t = 0; t < 32; t += 2){
    ATT_BODY(t, 0, 1)
    ATT_BODY(t + 1, 1, 0)
  }

  lrowA += __shfl_xor(lrowA, 32);
  lrowB += __shfl_xor(lrowB, 32);

  int b = bh >> 4, h = bh & 15;
  int q0 = qb * 256 + w * 64 + l31;
  float invA = 1.0f / lrowA;
  float invB = 1.0f / lrowB;
  size_t baseA = ((size_t)(b * 2048 + q0)) * 1024 + h * 64;
  size_t baseB = baseA + (size_t)32 * 1024;
  #pragma unroll
  for (int rg = 0; rg < 4; ++rg){
    short4 a0 = make_short4(f2bf(accA0[rg * 4 + 0] * invA), f2bf(accA0[rg * 4 + 1] * invA),
                            f2bf(accA0[rg * 4 + 2] * invA), f2bf(accA0[rg * 4 + 3] * invA));
    *(short4*)&OVb[baseA + rg * 8 + hi * 4] = a0;
    short4 a1 = make_short4(f2bf(accA1[rg * 4 + 0] * invA), f2bf(accA1[rg * 4 + 1] * invA),
                            f2bf(accA1[rg * 4 + 2] * invA), f2bf(accA1[rg * 4 + 3] * invA));
    *(short4*)&OVb[baseA + 32 + rg * 8 + hi * 4] = a1;
    short4 b0 = make_short4(f2bf(accB0[rg * 4 + 0] * invB), f2bf(accB0[rg * 4 + 1] * invB),
                            f2bf(accB0[rg * 4 + 2] * invB), f2bf(accB0[rg * 4 + 3] * invB));
    *(short4*)&OVb[baseB + rg * 8 + hi * 4] = b0;
    short4 b1 = make_short4(f2bf(accB1[rg * 4 + 0] * invB), f2bf(accB1[rg * 4 + 1] * invB),
                            f2bf(accB1[rg * 4 + 2] * invB), f2bf(accB1[rg * 4 + 3] * invB));
    *(short4*)&OVb[baseB + 32 + rg * 8 + hi * 4] = b1;
  }
}

extern "C" void kernel_launch(void* const* d_in, const int* in_sizes, int n_in,
                              void* d_out, int out_size, void* d_ws, size_t ws_size,
                              hipStream_t stream) {
  const float* query = (const float*)d_in[0];
  const float* key_  = (const float*)d_in[1];
  const float* value = (const float*)d_in[2];
  const float* W_Q = (const float*)d_in[3];
  const float* W_K = (const float*)d_in[4];
  const float* W_V = (const float*)d_in[5];
  const float* W_O = (const float*)d_in[6];
  const float* b_Q = (const float*)d_in[7];
  const float* b_K = (const float*)d_in[8];
  const float* b_V = (const float*)d_in[9];
  const float* b_O = (const float*)d_in[10];

  char* ws = (char*)d_ws;
  const size_t MB2 = 2097152, MB16 = 16777216;
  short* WqT = (short*)(ws + 0);
  short* WkT = (short*)(ws + MB2);
  short* WvT = (short*)(ws + 2 * MB2);
  short* WoT = (short*)(ws + 3 * MB2);
  short* Xq = (short*)(ws + 4 * MB2);
  short* Xk = (short*)(ws + 4 * MB2 + MB16);
  short* Xv = (short*)(ws + 4 * MB2 + 2 * MB16);
  bool big = ws_size >= (size_t)(4 * MB2 + 6 * MB16);
  short* Qb  = (short*)(ws + 4 * MB2 + 3 * MB16);
  short* Kb  = big ? (short*)(ws + 4 * MB2 + 4 * MB16) : Xq;
  short* Vtb = big ? (short*)(ws + 4 * MB2 + 5 * MB16) : Xk;
  short* OVb = Xv;   // attn output overwrites Xv (dead by then)

  prep_all<<<4608, 256, 0, stream>>>(query, key_, value, Xq, Xk, Xv,
                                     W_Q, W_K, W_V, WqT, WkT, WvT, W_O, WoT);

  if (big){
    proj3<<<dim3(64, 8, 3), 256, 0, stream>>>(Xq, Xk, Xv, WqT, WkT, WvT,
                                              b_Q, b_K, b_V, Qb, Kb, Vtb);
  } else {
    proj3<<<dim3(64, 8, 1), 256, 0, stream>>>(Xq, Xk, Xv, WqT, WkT, WvT, b_Q, b_K, b_V, Qb, Kb, Vtb);
    proj3<<<dim3(64, 8, 1), 256, 0, stream>>>(Xk, Xk, Xv, WkT, WkT, WvT, b_K, b_K, b_V, Kb, Kb, Vtb);
    proj3<<<dim3(64, 8, 1), 256, 0, stream>>>(Xv, Xk, Xv, WvT, WkT, WvT, b_V, b_K, b_V, Vtb, Kb, Vtb);
  }

  attn<<<512, 256, 0, stream>>>(Qb, Kb, Vtb, OVb);

  out_gemm<<<dim3(64, 8), 256, 0, stream>>>(OVb, WoT, b_O, (float*)d_out);
}

// Round 14
// 193.279 us; speedup vs baseline: 1.3465x; 1.0023x over previous
//
#include <hip/hip_runtime.h>
#include <hip/hip_bf16.h>

typedef __attribute__((ext_vector_type(8))) short bf16x8;
typedef __attribute__((ext_vector_type(4))) float f32x4;
typedef __attribute__((ext_vector_type(16))) float f32x16;
typedef __attribute__((ext_vector_type(4))) int i32x4;

#define LOG2E 1.4426950408889634f

__device__ __forceinline__ short f2bf(float f){
  unsigned u = __float_as_uint(f);
  u += 0x7fffu + ((u >> 16) & 1u);
  return (short)(u >> 16);
}
__device__ __forceinline__ unsigned cvtpk(float lo, float hi){
  unsigned r;
  asm("v_cvt_pk_bf16_f32 %0, %1, %2" : "=v"(r) : "v"(lo), "v"(hi));
  return r;
}
__device__ __forceinline__ void plswap(unsigned &a, unsigned &b){
  asm("v_permlane32_swap_b32 %0, %1" : "+v"(a), "+v"(b));
}
__device__ __forceinline__ void gl_lds16(const short* g, short* l){
  __builtin_amdgcn_global_load_lds((const __attribute__((address_space(1))) void*)g,
                                   (__attribute__((address_space(3))) void*)l, 16, 0, 0);
}

// ---------------- fused prep: xconv3 (bid<4096) + W_QKV transpose + W_O transpose ----------------
__global__ __launch_bounds__(256) void prep_all(const float* __restrict__ xq,
                                                const float* __restrict__ xk,
                                                const float* __restrict__ xv,
                                                short* __restrict__ oq,
                                                short* __restrict__ ok,
                                                short* __restrict__ ov,
                                                const float* __restrict__ Wq,
                                                const float* __restrict__ Wk,
                                                const float* __restrict__ Wv,
                                                short* __restrict__ WqT,
                                                short* __restrict__ WkT,
                                                short* __restrict__ WvT,
                                                const float* __restrict__ Wo,
                                                short* __restrict__ WoT){
  __shared__ short t[64][72];
  int bid = blockIdx.x;
  int tid = threadIdx.x;
  if (bid < 4096){
    int idx = (bid * 256 + tid) * 8;
    #pragma unroll
    for (int a = 0; a < 3; ++a){
      const float* x = a == 0 ? xq : (a == 1 ? xk : xv);
      short* o = a == 0 ? oq : (a == 1 ? ok : ov);
      float4 v0 = *(const float4*)&x[idx];
      float4 v1 = *(const float4*)&x[idx + 4];
      bf16x8 tt;
      tt[0]=f2bf(v0.x); tt[1]=f2bf(v0.y); tt[2]=f2bf(v0.z); tt[3]=f2bf(v0.w);
      tt[4]=f2bf(v1.x); tt[5]=f2bf(v1.y); tt[6]=f2bf(v1.z); tt[7]=f2bf(v1.w);
      *(bf16x8*)&o[idx] = tt;
    }
  } else if (bid < 4352){
    int b2 = bid - 4096;
    int h = b2 >> 4, et = b2 & 15;
    int er = tid >> 2, qc = (tid & 3) * 16;
    #pragma unroll
    for (int a = 0; a < 3; ++a){
      const float* W = a == 0 ? Wq : (a == 1 ? Wk : Wv);
      short* Wt = a == 0 ? WqT : (a == 1 ? WkT : WvT);
      if (a) __syncthreads();
      const float* src = W + h * 65536 + (et * 64 + er) * 64 + qc;
      #pragma unroll
      for (int v = 0; v < 4; ++v){
        float4 f = *(const float4*)(src + v * 4);
        t[qc + v * 4 + 0][er] = f2bf(f.x);
        t[qc + v * 4 + 1][er] = f2bf(f.y);
        t[qc + v * 4 + 2][er] = f2bf(f.z);
        t[qc + v * 4 + 3][er] = f2bf(f.w);
      }
      __syncthreads();
      bf16x8 o0 = *(const bf16x8*)&t[er][qc];
      bf16x8 o1 = *(const bf16x8*)&t[er][qc + 8];
      size_t dst = (size_t)(h * 64 + er) * 1024 + et * 64 + qc;
      *(bf16x8*)&Wt[dst] = o0;
      *(bf16x8*)&Wt[dst + 8] = o1;
    }
  } else {
    int b2 = bid - 4352;
    int bi = b2 >> 4, bj = b2 & 15;
    int r = tid >> 2, qc = (tid & 3) * 16;
    const float* src = Wo + (size_t)(bi * 64 + r) * 1024 + bj * 64 + qc;
    #pragma unroll
    for (int v = 0; v < 4; ++v){
      float4 f = *(const float4*)(src + v * 4);
      t[qc + v * 4 + 0][r] = f2bf(f.x);
      t[qc + v * 4 + 1][r] = f2bf(f.y);
      t[qc + v * 4 + 2][r] = f2bf(f.z);
      t[qc + v * 4 + 3][r] = f2bf(f.w);
    }
    __syncthreads();
    bf16x8 o0 = *(const bf16x8*)&t[r][qc];
    bf16x8 o1 = *(const bf16x8*)&t[r][qc + 8];
    size_t dst = (size_t)(bj * 64 + r) * 1024 + bi * 64 + qc;
    *(bf16x8*)&WoT[dst] = o0;
    *(bf16x8*)&WoT[dst + 8] = o1;
  }
}

// ---------------- fused QKV projection GEMM (blockIdx.z selects stream) ----------------
__global__ __launch_bounds__(256) void proj3(const short* __restrict__ Xq,
                                             const short* __restrict__ Xk,
                                             const short* __restrict__ Xv,
                                             const short* __restrict__ WqT,
                                             const short* __restrict__ WkT,
                                             const short* __restrict__ WvT,
                                             const float* __restrict__ bq,
                                             const float* __restrict__ bk,
                                             const float* __restrict__ bv,
                                             short* __restrict__ Oq,
                                             short* __restrict__ Ok,
                                             short* __restrict__ Ov){
  __shared__ short Al[128][64];
  __shared__ short Bl[128][64];
  int z = blockIdx.z;
  const short* A    = z == 0 ? Xq : (z == 1 ? Xk : Xv);
  const short* Wt   = z == 0 ? WqT : (z == 1 ? WkT : WvT);
  const float* bias = z == 0 ? bq : (z == 1 ? bk : bv);
  short* Out        = z == 0 ? Oq : (z == 1 ? Ok : Ov);
  float scale = z == 0 ? (LOG2E * 0.125f) : 1.0f;

  int tid = threadIdx.x;
  int bm0 = blockIdx.x * 128, bn0 = blockIdx.y * 128;
  int w = tid >> 6, lane = tid & 63;
  int wm = w >> 1, wn = w & 1;
  int r16 = lane & 15, kblk = lane >> 4;
  int srow = tid >> 3, schunk = tid & 7;

  f32x4 acc[4][4] = {};
  for (int kt = 0; kt < 16; ++kt){
    int k0 = kt * 64;
    __syncthreads();
    #pragma unroll
    for (int p = 0; p < 4; ++p){
      int row = p * 32 + srow;
      int sc = (schunk ^ (row & 7)) * 8;
      gl_lds16(A  + (size_t)(bm0 + row) * 1024 + k0 + sc, &Al[p * 32 + w * 8][0]);
      gl_lds16(Wt + (size_t)(bn0 + row) * 1024 + k0 + sc, &Bl[p * 32 + w * 8][0]);
    }
    __syncthreads();
    bf16x8 af[2][4], bfr[2][4];
    #pragma unroll
    for (int half = 0; half < 2; ++half){
      #pragma unroll
      for (int m = 0; m < 4; ++m){
        int r = wm * 64 + m * 16 + r16;
        af[half][m] = *(bf16x8*)&Al[r][(((half << 2) | kblk) ^ (r & 7)) * 8];
      }
      #pragma unroll
      for (int n = 0; n < 4; ++n){
        int r = wn * 64 + n * 16 + r16;
        bfr[half][n] = *(bf16x8*)&Bl[r][(((half << 2) | kblk) ^ (r & 7)) * 8];
      }
    }
    #pragma unroll
    for (int half = 0; half < 2; ++half)
      #pragma unroll
      for (int m = 0; m < 4; ++m)
        #pragma unroll
        for (int n = 0; n < 4; ++n)
          acc[m][n] = __builtin_amdgcn_mfma_f32_16x16x32_bf16(af[half][m], bfr[half][n], acc[m][n], 0, 0, 0);
  }
  if (z != 2){
    #pragma unroll
    for (int m = 0; m < 4; ++m){
      int grow0 = bm0 + wm * 64 + m * 16 + kblk * 4;
      #pragma unroll
      for (int n = 0; n < 4; ++n){
        int gcol = bn0 + wn * 64 + n * 16 + r16;
        float bv_ = bias[gcol];
        int h = gcol >> 6, d = gcol & 63;
        #pragma unroll
        for (int i = 0; i < 4; ++i){
          int grow = grow0 + i;
          int b = grow >> 11, s = grow & 2047;
          Out[(size_t)((b * 16 + h) * 2048 + s) * 64 + d] = f2bf((acc[m][n][i] + bv_) * scale);
        }
      }
    }
  } else {
    #pragma unroll
    for (int m = 0; m < 4; ++m){
      int grow0 = bm0 + wm * 64 + m * 16 + kblk * 4;
      int b = grow0 >> 11, s = grow0 & 2047;
      #pragma unroll
      for (int n = 0; n < 4; ++n){
        int gcol = bn0 + wn * 64 + n * 16 + r16;
        float bv_ = bias[gcol];
        int h = gcol >> 6, d = gcol & 63;
        short4 o = make_short4(f2bf(acc[m][n][0] + bv_),
                               f2bf(acc[m][n][1] + bv_),
                               f2bf(acc[m][n][2] + bv_),
                               f2bf(acc[m][n][3] + bv_));
        *(short4*)&Out[(size_t)((b * 16 + h) * 64 + d) * 2048 + s] = o;
      }
    }
  }
}

// ---------------- output projection GEMM ----------------
__global__ __launch_bounds__(256) void out_gemm(const short* __restrict__ A,
                                                const short* __restrict__ Wt,
                                                const float* __restrict__ bias,
                                                float* __restrict__ Out){
  __shared__ short Al[128][64];
  __shared__ short Bl[128][64];
  int tid = threadIdx.x;
  int bm0 = blockIdx.x * 128, bn0 = blockIdx.y * 128;
  int w = tid >> 6, lane = tid & 63;
  int wm = w >> 1, wn = w & 1;
  int r16 = lane & 15, kblk = lane >> 4;
  int srow = tid >> 3, schunk = tid & 7;
  f32x4 acc[4][4] = {};
  for (int kt = 0; kt < 16; ++kt){
    int k0 = kt * 64;
    __syncthreads();
    #pragma unroll
    for (int p = 0; p < 4; ++p){
      int row = p * 32 + srow;
      int sc = (schunk ^ (row & 7)) * 8;
      gl_lds16(A  + (size_t)(bm0 + row) * 1024 + k0 + sc, &Al[p * 32 + w * 8][0]);
      gl_lds16(Wt + (size_t)(bn0 + row) * 1024 + k0 + sc, &Bl[p * 32 + w * 8][0]);
    }
    __syncthreads();
    bf16x8 af[2][4], bfr[2][4];
    #pragma unroll
    for (int half = 0; half < 2; ++half){
      #pragma unroll
      for (int m = 0; m < 4; ++m){
        int r = wm * 64 + m * 16 + r16;
        af[half][m] = *(bf16x8*)&Al[r][(((half << 2) | kblk) ^ (r & 7)) * 8];
      }
      #pragma unroll
      for (int n = 0; n < 4; ++n){
        int r = wn * 64 + n * 16 + r16;
        bfr[half][n] = *(bf16x8*)&Bl[r][(((half << 2) | kblk) ^ (r & 7)) * 8];
      }
    }
    #pragma unroll
    for (int half = 0; half < 2; ++half)
      #pragma unroll
      for (int m = 0; m < 4; ++m)
        #pragma unroll
        for (int n = 0; n < 4; ++n)
          acc[m][n] = __builtin_amdgcn_mfma_f32_16x16x32_bf16(af[half][m], bfr[half][n], acc[m][n], 0, 0, 0);
  }
  #pragma unroll
  for (int m = 0; m < 4; ++m){
    int grow0 = bm0 + wm * 64 + m * 16 + kblk * 4;
    #pragma unroll
    for (int n = 0; n < 4; ++n){
      int gcol = bn0 + wn * 64 + n * 16 + r16;
      float bv = bias[gcol];
      #pragma unroll
      for (int i = 0; i < 4; ++i)
        Out[(size_t)(grow0 + i) * 1024 + gcol] = acc[m][n][i] + bv;
    }
  }
}

// ---------------- flash attention (round-9: K+V LDS dbuf, deferred cross-half shfl) ----------------
__device__ __forceinline__ f32x16 mfma32(bf16x8 a, bf16x8 b, f32x16 c){
  return __builtin_amdgcn_mfma_f32_32x32x16_bf16(a, b, c, 0, 0, 0);
}

__device__ __forceinline__ void sm_pack(f32x16& s0, f32x16& s1, float& lrow, bf16x8* pb){
  #pragma unroll
  for (int r = 0; r < 16; ++r) s0[r] = __builtin_amdgcn_exp2f(s0[r]);
  #pragma unroll
  for (int r = 0; r < 16; ++r) s1[r] = __builtin_amdgcn_exp2f(s1[r]);
  float u8_[8];
  #pragma unroll
  for (int r = 0; r < 8; ++r)
    u8_[r] = (s0[r] + s0[r + 8]) + (s1[r] + s1[r + 8]);
  float rs = ((u8_[0] + u8_[1]) + (u8_[2] + u8_[3])) + ((u8_[4] + u8_[5]) + (u8_[6] + u8_[7]));
  lrow += rs;                       // per-lane partial; cross-half shfl deferred to epilogue
  #pragma unroll
  for (int cc = 0; cc < 2; ++cc){
    int b0 = cc * 8;
    unsigned u0 = cvtpk(s0[b0 + 0], s0[b0 + 1]);
    unsigned u1 = cvtpk(s0[b0 + 2], s0[b0 + 3]);
    unsigned w0 = cvtpk(s0[b0 + 4], s0[b0 + 5]);
    unsigned w1 = cvtpk(s0[b0 + 6], s0[b0 + 7]);
    plswap(u0, w0); plswap(u1, w1);
    i32x4 pk0; pk0[0] = (int)u0; pk0[1] = (int)u1; pk0[2] = (int)w0; pk0[3] = (int)w1;
    pb[cc] = __builtin_bit_cast(bf16x8, pk0);
    unsigned y0 = cvtpk(s1[b0 + 0], s1[b0 + 1]);
    unsigned y1 = cvtpk(s1[b0 + 2], s1[b0 + 3]);
    unsigned z0 = cvtpk(s1[b0 + 4], s1[b0 + 5]);
    unsigned z1 = cvtpk(s1[b0 + 6], s1[b0 + 7]);
    plswap(y0, z0); plswap(y1, z1);
    i32x4 pk1; pk1[0] = (int)y0; pk1[1] = (int)y1; pk1[2] = (int)z0; pk1[3] = (int)z1;
    pb[2 + cc] = __builtin_bit_cast(bf16x8, pk1);
  }
}

#define ATT_BODY(T, CUR, NXT)                                                          \
  {                                                                                    \
    if ((T) + 1 < 32){                                                                 \
      _Pragma("unroll")                                                                \
      for (int p = 0; p < 2; ++p){                                                     \
        int row = p * 32 + srow;                                                       \
        gl_lds16(Kp + (size_t)(((T) + 1) * 64 + row) * 64 + sx, &Kl[NXT][p * 32 + w * 8][0]); \
        gl_lds16(Vp + (size_t)row * 2048 + ((T) + 1) * 64 + sx, &Vl[NXT][p * 32 + w * 8][0]); \
      }                                                                                \
    }                                                                                  \
    f32x16 sA0 = {}, sA1 = {}, sB0 = {}, sB1 = {};                                     \
    _Pragma("unroll")                                                                  \
    for (int c = 0; c < 4; ++c){                                                       \
      bf16x8 kf0 = *(const bf16x8*)&Kl[CUR][l31][rchunk[c]];                           \
      bf16x8 kf1 = *(const bf16x8*)&Kl[CUR][32 + l31][rchunk[c]];                      \
      sA0 = mfma32(kf0, qfA[c], sA0);                                                  \
      sA1 = mfma32(kf1, qfA[c], sA1);                                                  \
      sB0 = mfma32(kf0, qfB[c], sB0);                                                  \
      sB1 = mfma32(kf1, qfB[c], sB1);                                                  \
    }                                                                                  \
    bf16x8 pbA[4], pbB[4];                                                             \
    sm_pack(sA0, sA1, lrowA, pbA);                                                     \
    sm_pack(sB0, sB1, lrowB, pbB);                                                     \
    _Pragma("unroll")                                                                  \
    for (int c = 0; c < 4; ++c){                                                       \
      bf16x8 vf0 = *(const bf16x8*)&Vl[CUR][l31][rchunk[c]];                           \
      bf16x8 vf1 = *(const bf16x8*)&Vl[CUR][32 + l31][rchunk[c]];                      \
      accA0 = mfma32(vf0, pbA[c], accA0);                                              \
      accA1 = mfma32(vf1, pbA[c], accA1);                                              \
      accB0 = mfma32(vf0, pbB[c], accB0);                                              \
      accB1 = mfma32(vf1, pbB[c], accB1);                                              \
    }                                                                                  \
    __syncthreads();                                                                   \
  }

__global__ __launch_bounds__(256, 2) void attn(const short* __restrict__ Qb,
                                               const short* __restrict__ Kb,
                                               const short* __restrict__ Vtb,
                                               short* __restrict__ OVb){
  __shared__ short Kl[2][64][64];
  __shared__ short Vl[2][64][64];
  int tid = threadIdx.x;
  int w = tid >> 6, lane = tid & 63;
  int l31 = lane & 31, hi = lane >> 5;
  int bh = blockIdx.x & 63, qb = blockIdx.x >> 6;   // qb 0..7
  const short* Qp = Qb + ((size_t)bh * 2048 + qb * 256 + w * 64) * 64;
  const short* Kp = Kb + (size_t)bh * 2048 * 64;
  const short* Vp = Vtb + (size_t)bh * 64 * 2048;
  int srow = tid >> 3, schunk = tid & 7;
  int sx = (schunk ^ (srow & 7)) * 8;

  int rchunk[4];
  #pragma unroll
  for (int c = 0; c < 4; ++c) rchunk[c] = (((c << 1) | hi) ^ (l31 & 7)) * 8;

  #pragma unroll
  for (int p = 0; p < 2; ++p){
    int row = p * 32 + srow;
    gl_lds16(Kp + (size_t)row * 64 + sx, &Kl[0][p * 32 + w * 8][0]);
    gl_lds16(Vp + (size_t)row * 2048 + sx, &Vl[0][p * 32 + w * 8][0]);
  }

  bf16x8 qfA[4], qfB[4];
  #pragma unroll
  for (int c = 0; c < 4; ++c){
    qfA[c] = *(const bf16x8*)&Qp[l31 * 64 + c * 16 + hi * 8];
    qfB[c] = *(const bf16x8*)&Qp[(32 + l31) * 64 + c * 16 + hi * 8];
  }

  f32x16 accA0 = {}, accA1 = {}, accB0 = {}, accB1 = {};
  float lrowA = 0.f, lrowB = 0.f;
  __syncthreads();

  for (int t = 0; t < 32; t += 2){
    ATT_BODY(t, 0, 1)
    ATT_BODY(t + 1, 1, 0)
  }

  lrowA += __shfl_xor(lrowA, 32);
  lrowB += __shfl_xor(lrowB, 32);

  int b = bh >> 4, h = bh & 15;
  int q0 = qb * 256 + w * 64 + l31;
  float invA = 1.0f / lrowA;
  float invB = 1.0f / lrowB;
  size_t baseA = ((size_t)(b * 2048 + q0)) * 1024 + h * 64;
  size_t baseB = baseA + (size_t)32 * 1024;
  #pragma unroll
  for (int rg = 0; rg < 4; ++rg){
    short4 a0 = make_short4(f2bf(accA0[rg * 4 + 0] * invA), f2bf(accA0[rg * 4 + 1] * invA),
                            f2bf(accA0[rg * 4 + 2] * invA), f2bf(accA0[rg * 4 + 3] * invA));
    *(short4*)&OVb[baseA + rg * 8 + hi * 4] = a0;
    short4 a1 = make_short4(f2bf(accA1[rg * 4 + 0] * invA), f2bf(accA1[rg * 4 + 1] * invA),
                            f2bf(accA1[rg * 4 + 2] * invA), f2bf(accA1[rg * 4 + 3] * invA));
    *(short4*)&OVb[baseA + 32 + rg * 8 + hi * 4] = a1;
    short4 b0 = make_short4(f2bf(accB0[rg * 4 + 0] * invB), f2bf(accB0[rg * 4 + 1] * invB),
                            f2bf(accB0[rg * 4 + 2] * invB), f2bf(accB0[rg * 4 + 3] * invB));
    *(short4*)&OVb[baseB + rg * 8 + hi * 4] = b0;
    short4 b1 = make_short4(f2bf(accB1[rg * 4 + 0] * invB), f2bf(accB1[rg * 4 + 1] * invB),
                            f2bf(accB1[rg * 4 + 2] * invB), f2bf(accB1[rg * 4 + 3] * invB));
    *(short4*)&OVb[baseB + 32 + rg * 8 + hi * 4] = b1;
  }
}

extern "C" void kernel_launch(void* const* d_in, const int* in_sizes, int n_in,
                              void* d_out, int out_size, void* d_ws, size_t ws_size,
                              hipStream_t stream) {
  const float* query = (const float*)d_in[0];
  const float* key_  = (const float*)d_in[1];
  const float* value = (const float*)d_in[2];
  const float* W_Q = (const float*)d_in[3];
  const float* W_K = (const float*)d_in[4];
  const float* W_V = (const float*)d_in[5];
  const float* W_O = (const float*)d_in[6];
  const float* b_Q = (const float*)d_in[7];
  const float* b_K = (const float*)d_in[8];
  const float* b_V = (const float*)d_in[9];
  const float* b_O = (const float*)d_in[10];

  char* ws = (char*)d_ws;
  const size_t MB2 = 2097152, MB16 = 16777216;
  short* WqT = (short*)(ws + 0);
  short* WkT = (short*)(ws + MB2);
  short* WvT = (short*)(ws + 2 * MB2);
  short* WoT = (short*)(ws + 3 * MB2);
  short* Xq = (short*)(ws + 4 * MB2);
  short* Xk = (short*)(ws + 4 * MB2 + MB16);
  short* Xv = (short*)(ws + 4 * MB2 + 2 * MB16);
  bool big = ws_size >= (size_t)(4 * MB2 + 6 * MB16);
  short* Qb  = (short*)(ws + 4 * MB2 + 3 * MB16);
  short* Kb  = big ? (short*)(ws + 4 * MB2 + 4 * MB16) : Xq;
  short* Vtb = big ? (short*)(ws + 4 * MB2 + 5 * MB16) : Xk;
  short* OVb = Xv;   // attn output overwrites Xv (dead by then)

  prep_all<<<4608, 256, 0, stream>>>(query, key_, value, Xq, Xk, Xv,
                                     W_Q, W_K, W_V, WqT, WkT, WvT, W_O, WoT);

  if (big){
    proj3<<<dim3(64, 8, 3), 256, 0, stream>>>(Xq, Xk, Xv, WqT, WkT, WvT,
                                              b_Q, b_K, b_V, Qb, Kb, Vtb);
  } else {
    proj3<<<dim3(64, 8, 1), 256, 0, stream>>>(Xq, Xk, Xv, WqT, WkT, WvT, b_Q, b_K, b_V, Qb, Kb, Vtb);
    proj3<<<dim3(64, 8, 1), 256, 0, stream>>>(Xk, Xk, Xv, WkT, WkT, WvT, b_K, b_K, b_V, Kb, Kb, Vtb);
    proj3<<<dim3(64, 8, 1), 256, 0, stream>>>(Xv, Xk, Xv, WvT, WkT, WvT, b_V, b_K, b_V, Vtb, Kb, Vtb);
  }

  attn<<<512, 256, 0, stream>>>(Qb, Kb, Vtb, OVb);

  out_gemm<<<dim3(64, 8), 256, 0, stream>>>(OVb, WoT, b_O, (float*)d_out);
}